// Round 1
// baseline (633.815 us; speedup 1.0000x reference)
//
#include <hip/hip_runtime.h>
#include <math.h>

// Problem constants
#define BATCH 8
#define CH    256
#define HDIM  56
#define WDIM  56
#define HW    (HDIM*WDIM)          // 3136
#define MTOT  (BATCH*HW)           // 25088
#define GRP   8
#define GC    32
#define NP    9                    // K*K
#define NOFF  (GRP*NP*2)           // 144
#define NMSK  (GRP*NP)             // 72

// ---------------------------------------------------------------------------
// GEMM 1: v[m][n] = sum_k x[b][k][hw] * w_in[k][n] + b_in[n]
// A is "x-layout": element (m,k) at x[(b*CH + k)*HW + hw], m = b*HW + hw.
// n-fast thread mapping so NHWC stores coalesce.
// ---------------------------------------------------------------------------
__global__ __launch_bounds__(256)
void gemm_in_kernel(const float* __restrict__ x,
                    const float* __restrict__ w_in,
                    const float* __restrict__ b_in,
                    float* __restrict__ v)
{
    __shared__ alignas(16) float As[16][64];
    __shared__ alignas(16) float Bs[16][64];
    const int m0 = blockIdx.x * 64;
    const int n0 = blockIdx.y * 64;
    const int b  = m0 / HW;          // 3136 % 64 == 0: tile never crosses batch
    const int hw0 = m0 % HW;
    const int t = threadIdx.x;
    const int lk  = t >> 4;          // 0..15
    const int l4  = (t & 15) * 4;    // 0..60
    const int tn = t & 15, tm = t >> 4;
    float acc[4][4] = {};

    for (int k0 = 0; k0 < CH; k0 += 16) {
        const float4 a4 = *(const float4*)(x + ((size_t)b*CH + k0 + lk)*HW + hw0 + l4);
        const float4 b4 = *(const float4*)(w_in + (size_t)(k0 + lk)*CH + n0 + l4);
        *(float4*)&As[lk][l4] = a4;
        *(float4*)&Bs[lk][l4] = b4;
        __syncthreads();
        #pragma unroll
        for (int kk = 0; kk < 16; ++kk) {
            const float4 a = *(const float4*)&As[kk][tm*4];
            float bf[4];
            #pragma unroll
            for (int j = 0; j < 4; ++j) bf[j] = Bs[kk][tn + 16*j];
            #pragma unroll
            for (int i = 0; i < 4; ++i) {
                const float av = ((const float*)&a)[i];
                #pragma unroll
                for (int j = 0; j < 4; ++j) acc[i][j] += av * bf[j];
            }
        }
        __syncthreads();
    }
    #pragma unroll
    for (int i = 0; i < 4; ++i) {
        const int m = m0 + tm*4 + i;
        #pragma unroll
        for (int j = 0; j < 4; ++j) {
            const int nn = n0 + tn + 16*j;
            v[(size_t)m*CH + nn] = acc[i][j] + b_in[nn];
        }
    }
}

// ---------------------------------------------------------------------------
// Fused depthwise 3x3 (NCHW) + bias + LayerNorm(C) + exact GELU -> f (NHWC)
// One block per spatial position, thread = channel.
// ---------------------------------------------------------------------------
__global__ __launch_bounds__(256)
void dw_ln_gelu_kernel(const float* __restrict__ x,
                       const float* __restrict__ dw_w,
                       const float* __restrict__ dw_b,
                       const float* __restrict__ ln_g,
                       const float* __restrict__ ln_b,
                       float* __restrict__ f)
{
    const int n = blockIdx.x;             // 0..MTOT-1
    const int b = n / HW, hw = n % HW;
    const int h = hw / WDIM, w = hw % WDIM;
    const int c = threadIdx.x;

    const float* xp = x + ((size_t)b*CH + c)*HW;
    const float* wp = dw_w + c*9;
    float acc = dw_b[c];
    #pragma unroll
    for (int kh = 0; kh < 3; ++kh) {
        const int hh = h + kh - 1;
        if (hh < 0 || hh >= HDIM) continue;
        #pragma unroll
        for (int kw = 0; kw < 3; ++kw) {
            const int ww = w + kw - 1;
            if (ww < 0 || ww >= WDIM) continue;
            acc += xp[hh*WDIM + ww] * wp[kh*3 + kw];
        }
    }

    // block-wide LN reduction (sum, sumsq over 256 channels)
    float s1 = acc, s2 = acc * acc;
    #pragma unroll
    for (int off = 32; off > 0; off >>= 1) {
        s1 += __shfl_down(s1, off);
        s2 += __shfl_down(s2, off);
    }
    __shared__ float r1[4], r2[4];
    const int wave = threadIdx.x >> 6, lane = threadIdx.x & 63;
    if (lane == 0) { r1[wave] = s1; r2[wave] = s2; }
    __syncthreads();
    if (threadIdx.x == 0) {
        float a = r1[0] + r1[1] + r1[2] + r1[3];
        float q = r2[0] + r2[1] + r2[2] + r2[3];
        r1[0] = a; r2[0] = q;
    }
    __syncthreads();
    const float mean = r1[0] * (1.0f/256.0f);
    const float var  = r2[0] * (1.0f/256.0f) - mean*mean;
    float xn = (acc - mean) * rsqrtf(var + 1e-5f) * ln_g[c] + ln_b[c];
    // exact GELU
    const float g = 0.5f * xn * (1.0f + erff(xn * 0.70710678118654752f));
    f[(size_t)n*CH + c] = g;
}

// ---------------------------------------------------------------------------
// GEMM (A row-major [M,256]) -> Cout [M,N] = A @ Bw + bias. Generic N <= 64*gridDim.y.
// ---------------------------------------------------------------------------
__global__ __launch_bounds__(256)
void gemm_rowA_kernel(const float* __restrict__ A,
                      const float* __restrict__ Bw,
                      const float* __restrict__ bias,
                      float* __restrict__ Cout,
                      const int N)
{
    __shared__ alignas(16) float As[16][64];
    __shared__ alignas(16) float Bs[16][64];
    const int m0 = blockIdx.x * 64;
    const int n0 = blockIdx.y * 64;
    const int t = threadIdx.x;
    const int am = t >> 2, ak4 = (t & 3) * 4;      // A tile load
    const int lk = t >> 4, ln4 = (t & 15) * 4;     // B tile load
    const int tn = t & 15, tm = t >> 4;            // n-fast compute map
    float acc[4][4] = {};

    for (int k0 = 0; k0 < CH; k0 += 16) {
        const float4 a4 = *(const float4*)(A + (size_t)(m0 + am)*CH + k0 + ak4);
        float bb[4];
        #pragma unroll
        for (int j = 0; j < 4; ++j) {
            const int nn = n0 + ln4 + j;
            bb[j] = (nn < N) ? Bw[(size_t)(k0 + lk)*N + nn] : 0.0f;
        }
        #pragma unroll
        for (int j = 0; j < 4; ++j) As[ak4 + j][am] = ((const float*)&a4)[j];
        #pragma unroll
        for (int j = 0; j < 4; ++j) Bs[lk][ln4 + j] = bb[j];
        __syncthreads();
        #pragma unroll
        for (int kk = 0; kk < 16; ++kk) {
            const float4 a = *(const float4*)&As[kk][tm*4];
            float bf[4];
            #pragma unroll
            for (int j = 0; j < 4; ++j) bf[j] = Bs[kk][tn + 16*j];
            #pragma unroll
            for (int i = 0; i < 4; ++i) {
                const float av = ((const float*)&a)[i];
                #pragma unroll
                for (int j = 0; j < 4; ++j) acc[i][j] += av * bf[j];
            }
        }
        __syncthreads();
    }
    #pragma unroll
    for (int i = 0; i < 4; ++i) {
        const int m = m0 + tm*4 + i;
        #pragma unroll
        for (int j = 0; j < 4; ++j) {
            const int nn = n0 + tn + 16*j;
            if (nn < N) Cout[(size_t)m*N + nn] = acc[i][j] + bias[nn];
        }
    }
}

// ---------------------------------------------------------------------------
// Deformable sampling. Block per spatial position (b,h,w); thread = channel
// (g = t/32, gc = t%32). Softmax over P=9 done in LDS. Reads v (NHWC),
// writes s (NHWC). Zero-padded border handled via interior check: any
// corner index outside [1,57)^2 (padded coords) contributes 0.
// ---------------------------------------------------------------------------
__global__ __launch_bounds__(256)
void sample_kernel(const float* __restrict__ v,
                   const float* __restrict__ offb,
                   const float* __restrict__ mskb,
                   float* __restrict__ s)
{
    const int n = blockIdx.x;
    const int b = n / HW, hw = n % HW;
    const int h = hw / WDIM, w = hw % WDIM;
    const int t = threadIdx.x;

    __shared__ float loff[NOFF];
    __shared__ float lm[NMSK];
    if (t < NOFF)              loff[t]        = offb[(size_t)n*NOFF + t];
    else if (t < NOFF + NMSK)  lm[t - NOFF]   = mskb[(size_t)n*NMSK + (t - NOFF)];
    __syncthreads();
    if (t < GRP) {
        float mx = -1e30f;
        #pragma unroll
        for (int p = 0; p < NP; ++p) mx = fmaxf(mx, lm[t*NP + p]);
        float sum = 0.0f;
        #pragma unroll
        for (int p = 0; p < NP; ++p) { const float e = __expf(lm[t*NP + p] - mx); lm[t*NP + p] = e; sum += e; }
        const float inv = 1.0f / sum;
        #pragma unroll
        for (int p = 0; p < NP; ++p) lm[t*NP + p] *= inv;
    }
    __syncthreads();

    const int g = t >> 5;
    const float* vb = v + (size_t)b*HW*CH;
    float acc = 0.0f;
    #pragma unroll
    for (int p = 0; p < NP; ++p) {
        const float ox = loff[g*18 + p*2 + 0];
        const float oy = loff[g*18 + p*2 + 1];
        const float m  = lm[g*NP + p];
        // padded pixel coords: px = w + p/3 + ox ; py = h + p%3 + oy
        const float px = (float)(w + p/3) + ox;
        const float py = (float)(h + p%3) + oy;
        const float fx = floorf(px), fy = floorf(py);
        const float wx = px - fx, wy = py - fy;
        const int x0 = (int)fx, y0 = (int)fy;
        const int x1 = x0 + 1, y1 = y0 + 1;

        float v00 = 0.f, v01 = 0.f, v10 = 0.f, v11 = 0.f;
        // interior of padded array is [1, 57) in both dims; v index = coord-1
        if (y0 >= 1 && y0 < 57) {
            if (x0 >= 1 && x0 < 57) v00 = vb[((size_t)(y0-1)*WDIM + (x0-1))*CH + t];
            if (x1 >= 1 && x1 < 57) v01 = vb[((size_t)(y0-1)*WDIM + (x1-1))*CH + t];
        }
        if (y1 >= 1 && y1 < 57) {
            if (x0 >= 1 && x0 < 57) v10 = vb[((size_t)(y1-1)*WDIM + (x0-1))*CH + t];
            if (x1 >= 1 && x1 < 57) v11 = vb[((size_t)(y1-1)*WDIM + (x1-1))*CH + t];
        }
        const float bl = v00*(1.0f-wx)*(1.0f-wy) + v01*wx*(1.0f-wy)
                       + v10*(1.0f-wx)*wy        + v11*wx*wy;
        acc += m * bl;
    }
    s[(size_t)n*CH + t] = acc;
}

// ---------------------------------------------------------------------------
// GEMM out: y = SiLU(BN(s @ w_out + b_out)), stored NCHW.
// m-fast thread mapping so NCHW stores coalesce along hw.
// ---------------------------------------------------------------------------
__global__ __launch_bounds__(256)
void gemm_out_kernel(const float* __restrict__ A,     // s [MTOT,256]
                     const float* __restrict__ Bw,    // w_out [256,256]
                     const float* __restrict__ bias,  // b_out
                     const float* __restrict__ bn_g,
                     const float* __restrict__ bn_b,
                     const float* __restrict__ bn_mean,
                     const float* __restrict__ bn_var,
                     float* __restrict__ y)           // [B,256,3136]
{
    __shared__ alignas(16) float As[16][64];
    __shared__ alignas(16) float Bs[16][64];
    const int m0 = blockIdx.x * 64;
    const int n0 = blockIdx.y * 64;
    const int t = threadIdx.x;
    const int am = t >> 2, ak4 = (t & 3) * 4;
    const int lk = t >> 4, ln4 = (t & 15) * 4;
    const int tm = t & 15, tn = t >> 4;   // m-fast compute map
    float acc[4][4] = {};

    for (int k0 = 0; k0 < CH; k0 += 16) {
        const float4 a4 = *(const float4*)(A + (size_t)(m0 + am)*CH + k0 + ak4);
        const float4 b4 = *(const float4*)(Bw + (size_t)(k0 + lk)*CH + n0 + ln4);
        #pragma unroll
        for (int j = 0; j < 4; ++j) As[ak4 + j][am] = ((const float*)&a4)[j];
        *(float4*)&Bs[lk][ln4] = b4;
        __syncthreads();
        #pragma unroll
        for (int kk = 0; kk < 16; ++kk) {
            float av[4];
            #pragma unroll
            for (int i = 0; i < 4; ++i) av[i] = As[kk][tm + 16*i];
            const float4 bv = *(const float4*)&Bs[kk][tn*4];
            #pragma unroll
            for (int i = 0; i < 4; ++i) {
                #pragma unroll
                for (int j = 0; j < 4; ++j)
                    acc[i][j] += av[i] * ((const float*)&bv)[j];
            }
        }
        __syncthreads();
    }
    const int b = m0 / HW;
    const int hw0 = m0 % HW;
    #pragma unroll
    for (int j = 0; j < 4; ++j) {
        const int nn = n0 + tn*4 + j;
        const float sc = bn_g[nn] * rsqrtf(bn_var[nn] + 1e-5f);
        const float sh = bn_b[nn] - bn_mean[nn] * sc;
        #pragma unroll
        for (int i = 0; i < 4; ++i) {
            const int hwp = hw0 + tm + 16*i;
            float val = acc[i][j] + bias[nn];
            val = val * sc + sh;
            const float out = val / (1.0f + expf(-val));   // SiLU
            y[((size_t)b*CH + nn)*HW + hwp] = out;
        }
    }
}

extern "C" void kernel_launch(void* const* d_in, const int* in_sizes, int n_in,
                              void* d_out, int out_size, void* d_ws, size_t ws_size,
                              hipStream_t stream) {
    const float* x      = (const float*)d_in[0];
    const float* w_in   = (const float*)d_in[1];
    const float* b_in   = (const float*)d_in[2];
    const float* dw_w   = (const float*)d_in[3];
    const float* dw_b   = (const float*)d_in[4];
    const float* ln_g   = (const float*)d_in[5];
    const float* ln_b   = (const float*)d_in[6];
    const float* w_off  = (const float*)d_in[7];
    const float* b_off  = (const float*)d_in[8];
    const float* w_mask = (const float*)d_in[9];
    const float* b_mask = (const float*)d_in[10];
    const float* w_out  = (const float*)d_in[11];
    const float* b_out  = (const float*)d_in[12];
    const float* bn_g   = (const float*)d_in[13];
    const float* bn_b   = (const float*)d_in[14];
    const float* bn_mean= (const float*)d_in[15];
    const float* bn_var = (const float*)d_in[16];
    float* out = (float*)d_out;

    float* ws   = (float*)d_ws;
    float* v    = ws;                                   // MTOT*CH
    float* f    = v + (size_t)MTOT*CH;                  // MTOT*CH
    float* offb = f + (size_t)MTOT*CH;                  // MTOT*NOFF
    float* mskb = offb + (size_t)MTOT*NOFF;             // MTOT*NMSK
    float* s    = f;                                    // reuse f buffer

    const dim3 blk(256);
    gemm_in_kernel<<<dim3(MTOT/64, CH/64), blk, 0, stream>>>(x, w_in, b_in, v);
    dw_ln_gelu_kernel<<<dim3(MTOT), blk, 0, stream>>>(x, dw_w, dw_b, ln_g, ln_b, f);
    gemm_rowA_kernel<<<dim3(MTOT/64, (NOFF + 63)/64), blk, 0, stream>>>(f, w_off, b_off, offb, NOFF);
    gemm_rowA_kernel<<<dim3(MTOT/64, (NMSK + 63)/64), blk, 0, stream>>>(f, w_mask, b_mask, mskb, NMSK);
    sample_kernel<<<dim3(MTOT), blk, 0, stream>>>(v, offb, mskb, s);
    gemm_out_kernel<<<dim3(MTOT/64, CH/64), blk, 0, stream>>>(s, w_out, b_out, bn_g, bn_b, bn_mean, bn_var, out);
}

// Round 3
// 422.098 us; speedup vs baseline: 1.5016x; 1.5016x over previous
//
#include <hip/hip_runtime.h>
#include <math.h>

// Problem constants
#define BATCH 8
#define CH    256
#define HDIM  56
#define WDIM  56
#define HW    (HDIM*WDIM)          // 3136
#define MTOT  (BATCH*HW)           // 25088
#define GRP   8
#define GC    32
#define NP    9                    // K*K
#define NOFF  (GRP*NP*2)           // 144
#define NMSK  (GRP*NP)             // 72

// ---------------------------------------------------------------------------
// GEMM 1: v[m][n] = sum_k x[b][k][hw] * w_in[k][n] + b_in[n]
// ---------------------------------------------------------------------------
__global__ __launch_bounds__(256)
void gemm_in_kernel(const float* __restrict__ x,
                    const float* __restrict__ w_in,
                    const float* __restrict__ b_in,
                    float* __restrict__ v)
{
    __shared__ alignas(16) float As[16][64];
    __shared__ alignas(16) float Bs[16][64];
    const int m0 = blockIdx.x * 64;
    const int n0 = blockIdx.y * 64;
    const int b  = m0 / HW;          // 3136 % 64 == 0: tile never crosses batch
    const int hw0 = m0 % HW;
    const int t = threadIdx.x;
    const int lk  = t >> 4;          // 0..15
    const int l4  = (t & 15) * 4;    // 0..60
    const int tn = t & 15, tm = t >> 4;
    float acc[4][4] = {};

    for (int k0 = 0; k0 < CH; k0 += 16) {
        const float4 a4 = *(const float4*)(x + ((size_t)b*CH + k0 + lk)*HW + hw0 + l4);
        const float4 b4 = *(const float4*)(w_in + (size_t)(k0 + lk)*CH + n0 + l4);
        *(float4*)&As[lk][l4] = a4;
        *(float4*)&Bs[lk][l4] = b4;
        __syncthreads();
        #pragma unroll
        for (int kk = 0; kk < 16; ++kk) {
            const float4 a = *(const float4*)&As[kk][tm*4];
            float bf[4];
            #pragma unroll
            for (int j = 0; j < 4; ++j) bf[j] = Bs[kk][tn + 16*j];
            #pragma unroll
            for (int i = 0; i < 4; ++i) {
                const float av = ((const float*)&a)[i];
                #pragma unroll
                for (int j = 0; j < 4; ++j) acc[i][j] += av * bf[j];
            }
        }
        __syncthreads();
    }
    #pragma unroll
    for (int i = 0; i < 4; ++i) {
        const int m = m0 + tm*4 + i;
        #pragma unroll
        for (int j = 0; j < 4; ++j) {
            const int nn = n0 + tn + 16*j;
            v[(size_t)m*CH + nn] = acc[i][j] + b_in[nn];
        }
    }
}

// ---------------------------------------------------------------------------
// Fused depthwise 3x3 + bias + LayerNorm(C) + exact GELU -> f (NHWC)
// Block per (b,h) row. 256 threads = 4 waves; each wave handles one channel
// per iteration with coalesced row loads. Horizontal halo via __shfl (no
// LDS race). Results transposed through an LDS tile [pos][channel] so LN
// (over channels) and the NHWC store coalesce.
// ---------------------------------------------------------------------------
__global__ __launch_bounds__(256)
void dw_ln_gelu_kernel(const float* __restrict__ x,
                       const float* __restrict__ dw_w,
                       const float* __restrict__ dw_b,
                       const float* __restrict__ ln_g,
                       const float* __restrict__ ln_b,
                       float* __restrict__ f)
{
    __shared__ float tile[WDIM][CH + 1];    // 56 x 257 floats (57.5 KB)
    __shared__ float red1[WDIM][4], red2[WDIM][4];
    __shared__ float meanA[WDIM], rstdA[WDIM];

    const int h = blockIdx.x;
    const int b = blockIdx.y;
    const int t = threadIdx.x;
    const int lane = t & 63;
    const int wv   = t >> 6;               // wave id 0..3

    // ---- Phase 1: depthwise conv, 4 channels (one per wave) per iteration
    for (int cg = 0; cg < CH / 4; ++cg) {
        const int c = cg * 4 + wv;
        const float* xp = x + ((size_t)b * CH + c) * HW;
        // coalesced row loads: lane w holds pixel (hh, w); lanes >=56 hold 0
        float rowv[3];
        #pragma unroll
        for (int r = 0; r < 3; ++r) {
            const int hh = h + r - 1;
            rowv[r] = (lane < WDIM && hh >= 0 && hh < HDIM) ? xp[hh * WDIM + lane] : 0.0f;
        }
        const float* wp = dw_w + c * 9;     // wave-uniform -> scalar loads
        float acc = dw_b[c];
        #pragma unroll
        for (int r = 0; r < 3; ++r) {
            float L = __shfl_up(rowv[r], 1);     // lane-1's pixel
            float R = __shfl_down(rowv[r], 1);   // lane+1's pixel (lane55 <- lane56 == 0)
            if (lane == 0) L = 0.0f;             // left border
            acc += L * wp[r * 3 + 0] + rowv[r] * wp[r * 3 + 1] + R * wp[r * 3 + 2];
        }
        if (lane < WDIM)
            tile[lane][c] = acc;            // stride 257: conflict-free
    }
    __syncthreads();

    // ---- Phase 2: LN statistics per position (56 positions x 256 channels)
    if (t < 224) {
        const int p = t >> 2, q = t & 3;
        float s1 = 0.0f, s2 = 0.0f;
        #pragma unroll 8
        for (int i = 0; i < 64; ++i) {
            const float v = tile[p][q * 64 + i];
            s1 += v; s2 += v * v;
        }
        red1[p][q] = s1; red2[p][q] = s2;
    }
    __syncthreads();
    if (t < WDIM) {
        const float s1 = red1[t][0] + red1[t][1] + red1[t][2] + red1[t][3];
        const float s2 = red2[t][0] + red2[t][1] + red2[t][2] + red2[t][3];
        const float m = s1 * (1.0f / 256.0f);
        const float var = s2 * (1.0f / 256.0f) - m * m;
        meanA[t] = m;
        rstdA[t] = rsqrtf(var + 1e-5f);
    }
    __syncthreads();

    // ---- Phase 3: normalize + GELU + coalesced NHWC store
    const float gam = ln_g[t], bet = ln_b[t];
    const size_t n0 = (size_t)(b * HDIM + h) * WDIM;
    for (int p = 0; p < WDIM; ++p) {
        const float xn = (tile[p][t] - meanA[p]) * rstdA[p] * gam + bet;
        const float g = 0.5f * xn * (1.0f + erff(xn * 0.70710678118654752f));
        f[(n0 + p) * CH + t] = g;
    }
}

// ---------------------------------------------------------------------------
// GEMM (A row-major [M,256]) -> Cout [M,N] = A @ Bw + bias.
// ---------------------------------------------------------------------------
__global__ __launch_bounds__(256)
void gemm_rowA_kernel(const float* __restrict__ A,
                      const float* __restrict__ Bw,
                      const float* __restrict__ bias,
                      float* __restrict__ Cout,
                      const int N)
{
    __shared__ alignas(16) float As[16][64];
    __shared__ alignas(16) float Bs[16][64];
    const int m0 = blockIdx.x * 64;
    const int n0 = blockIdx.y * 64;
    const int t = threadIdx.x;
    const int am = t >> 2, ak4 = (t & 3) * 4;      // A tile load
    const int lk = t >> 4, ln4 = (t & 15) * 4;     // B tile load
    const int tn = t & 15, tm = t >> 4;            // n-fast compute map
    float acc[4][4] = {};

    for (int k0 = 0; k0 < CH; k0 += 16) {
        const float4 a4 = *(const float4*)(A + (size_t)(m0 + am)*CH + k0 + ak4);
        float bb[4];
        #pragma unroll
        for (int j = 0; j < 4; ++j) {
            const int nn = n0 + ln4 + j;
            bb[j] = (nn < N) ? Bw[(size_t)(k0 + lk)*N + nn] : 0.0f;
        }
        #pragma unroll
        for (int j = 0; j < 4; ++j) As[ak4 + j][am] = ((const float*)&a4)[j];
        #pragma unroll
        for (int j = 0; j < 4; ++j) Bs[lk][ln4 + j] = bb[j];
        __syncthreads();
        #pragma unroll
        for (int kk = 0; kk < 16; ++kk) {
            const float4 a = *(const float4*)&As[kk][tm*4];
            float bf[4];
            #pragma unroll
            for (int j = 0; j < 4; ++j) bf[j] = Bs[kk][tn + 16*j];
            #pragma unroll
            for (int i = 0; i < 4; ++i) {
                const float av = ((const float*)&a)[i];
                #pragma unroll
                for (int j = 0; j < 4; ++j) acc[i][j] += av * bf[j];
            }
        }
        __syncthreads();
    }
    #pragma unroll
    for (int i = 0; i < 4; ++i) {
        const int m = m0 + tm*4 + i;
        #pragma unroll
        for (int j = 0; j < 4; ++j) {
            const int nn = n0 + tn + 16*j;
            if (nn < N) Cout[(size_t)m*N + nn] = acc[i][j] + bias[nn];
        }
    }
}

// ---------------------------------------------------------------------------
// Deformable sampling. Block per spatial position; thread = channel.
// ---------------------------------------------------------------------------
__global__ __launch_bounds__(256)
void sample_kernel(const float* __restrict__ v,
                   const float* __restrict__ offb,
                   const float* __restrict__ mskb,
                   float* __restrict__ s)
{
    const int n = blockIdx.x;
    const int b = n / HW, hw = n % HW;
    const int h = hw / WDIM, w = hw % WDIM;
    const int t = threadIdx.x;

    __shared__ float loff[NOFF];
    __shared__ float lm[NMSK];
    if (t < NOFF)              loff[t]        = offb[(size_t)n*NOFF + t];
    else if (t < NOFF + NMSK)  lm[t - NOFF]   = mskb[(size_t)n*NMSK + (t - NOFF)];
    __syncthreads();
    if (t < GRP) {
        float mx = -1e30f;
        #pragma unroll
        for (int p = 0; p < NP; ++p) mx = fmaxf(mx, lm[t*NP + p]);
        float sum = 0.0f;
        #pragma unroll
        for (int p = 0; p < NP; ++p) { const float e = __expf(lm[t*NP + p] - mx); lm[t*NP + p] = e; sum += e; }
        const float inv = 1.0f / sum;
        #pragma unroll
        for (int p = 0; p < NP; ++p) lm[t*NP + p] *= inv;
    }
    __syncthreads();

    const int g = t >> 5;
    const float* vb = v + (size_t)b*HW*CH;
    float acc = 0.0f;
    #pragma unroll
    for (int p = 0; p < NP; ++p) {
        const float ox = loff[g*18 + p*2 + 0];
        const float oy = loff[g*18 + p*2 + 1];
        const float m  = lm[g*NP + p];
        const float px = (float)(w + p/3) + ox;
        const float py = (float)(h + p%3) + oy;
        const float fx = floorf(px), fy = floorf(py);
        const float wx = px - fx, wy = py - fy;
        const int x0 = (int)fx, y0 = (int)fy;
        const int x1 = x0 + 1, y1 = y0 + 1;

        float v00 = 0.f, v01 = 0.f, v10 = 0.f, v11 = 0.f;
        if (y0 >= 1 && y0 < 57) {
            if (x0 >= 1 && x0 < 57) v00 = vb[((size_t)(y0-1)*WDIM + (x0-1))*CH + t];
            if (x1 >= 1 && x1 < 57) v01 = vb[((size_t)(y0-1)*WDIM + (x1-1))*CH + t];
        }
        if (y1 >= 1 && y1 < 57) {
            if (x0 >= 1 && x0 < 57) v10 = vb[((size_t)(y1-1)*WDIM + (x0-1))*CH + t];
            if (x1 >= 1 && x1 < 57) v11 = vb[((size_t)(y1-1)*WDIM + (x1-1))*CH + t];
        }
        const float bl = v00*(1.0f-wx)*(1.0f-wy) + v01*wx*(1.0f-wy)
                       + v10*(1.0f-wx)*wy        + v11*wx*wy;
        acc += m * bl;
    }
    s[(size_t)n*CH + t] = acc;
}

// ---------------------------------------------------------------------------
// GEMM out: y = SiLU(BN(s @ w_out + b_out)), stored NCHW.
// ---------------------------------------------------------------------------
__global__ __launch_bounds__(256)
void gemm_out_kernel(const float* __restrict__ A,     // s [MTOT,256]
                     const float* __restrict__ Bw,    // w_out [256,256]
                     const float* __restrict__ bias,  // b_out
                     const float* __restrict__ bn_g,
                     const float* __restrict__ bn_b,
                     const float* __restrict__ bn_mean,
                     const float* __restrict__ bn_var,
                     float* __restrict__ y)           // [B,256,3136]
{
    __shared__ alignas(16) float As[16][64];
    __shared__ alignas(16) float Bs[16][64];
    const int m0 = blockIdx.x * 64;
    const int n0 = blockIdx.y * 64;
    const int t = threadIdx.x;
    const int am = t >> 2, ak4 = (t & 3) * 4;
    const int lk = t >> 4, ln4 = (t & 15) * 4;
    const int tm = t & 15, tn = t >> 4;   // m-fast compute map
    float acc[4][4] = {};

    for (int k0 = 0; k0 < CH; k0 += 16) {
        const float4 a4 = *(const float4*)(A + (size_t)(m0 + am)*CH + k0 + ak4);
        const float4 b4 = *(const float4*)(Bw + (size_t)(k0 + lk)*CH + n0 + ln4);
        #pragma unroll
        for (int j = 0; j < 4; ++j) As[ak4 + j][am] = ((const float*)&a4)[j];
        *(float4*)&Bs[lk][ln4] = b4;
        __syncthreads();
        #pragma unroll
        for (int kk = 0; kk < 16; ++kk) {
            float av[4];
            #pragma unroll
            for (int i = 0; i < 4; ++i) av[i] = As[kk][tm + 16*i];
            const float4 bv = *(const float4*)&Bs[kk][tn*4];
            #pragma unroll
            for (int i = 0; i < 4; ++i) {
                #pragma unroll
                for (int j = 0; j < 4; ++j)
                    acc[i][j] += av[i] * ((const float*)&bv)[j];
            }
        }
        __syncthreads();
    }
    const int b = m0 / HW;
    const int hw0 = m0 % HW;
    #pragma unroll
    for (int j = 0; j < 4; ++j) {
        const int nn = n0 + tn*4 + j;
        const float sc = bn_g[nn] * rsqrtf(bn_var[nn] + 1e-5f);
        const float sh = bn_b[nn] - bn_mean[nn] * sc;
        #pragma unroll
        for (int i = 0; i < 4; ++i) {
            const int hwp = hw0 + tm + 16*i;
            float val = acc[i][j] + bias[nn];
            val = val * sc + sh;
            const float out = val / (1.0f + expf(-val));   // SiLU
            y[((size_t)b*CH + nn)*HW + hwp] = out;
        }
    }
}

extern "C" void kernel_launch(void* const* d_in, const int* in_sizes, int n_in,
                              void* d_out, int out_size, void* d_ws, size_t ws_size,
                              hipStream_t stream) {
    const float* x      = (const float*)d_in[0];
    const float* w_in   = (const float*)d_in[1];
    const float* b_in   = (const float*)d_in[2];
    const float* dw_w   = (const float*)d_in[3];
    const float* dw_b   = (const float*)d_in[4];
    const float* ln_g   = (const float*)d_in[5];
    const float* ln_b   = (const float*)d_in[6];
    const float* w_off  = (const float*)d_in[7];
    const float* b_off  = (const float*)d_in[8];
    const float* w_mask = (const float*)d_in[9];
    const float* b_mask = (const float*)d_in[10];
    const float* w_out  = (const float*)d_in[11];
    const float* b_out  = (const float*)d_in[12];
    const float* bn_g   = (const float*)d_in[13];
    const float* bn_b   = (const float*)d_in[14];
    const float* bn_mean= (const float*)d_in[15];
    const float* bn_var = (const float*)d_in[16];
    float* out = (float*)d_out;

    float* ws   = (float*)d_ws;
    float* v    = ws;                                   // MTOT*CH
    float* f    = v + (size_t)MTOT*CH;                  // MTOT*CH
    float* offb = f + (size_t)MTOT*CH;                  // MTOT*NOFF
    float* mskb = offb + (size_t)MTOT*NOFF;             // MTOT*NMSK
    float* s    = f;                                    // reuse f buffer

    const dim3 blk(256);
    gemm_in_kernel<<<dim3(MTOT/64, CH/64), blk, 0, stream>>>(x, w_in, b_in, v);
    dw_ln_gelu_kernel<<<dim3(HDIM, BATCH), blk, 0, stream>>>(x, dw_w, dw_b, ln_g, ln_b, f);
    gemm_rowA_kernel<<<dim3(MTOT/64, (NOFF + 63)/64), blk, 0, stream>>>(f, w_off, b_off, offb, NOFF);
    gemm_rowA_kernel<<<dim3(MTOT/64, (NMSK + 63)/64), blk, 0, stream>>>(f, w_mask, b_mask, mskb, NMSK);
    sample_kernel<<<dim3(MTOT), blk, 0, stream>>>(v, offb, mskb, s);
    gemm_out_kernel<<<dim3(MTOT/64, CH/64), blk, 0, stream>>>(s, w_out, b_out, bn_g, bn_b, bn_mean, bn_var, out);
}

// Round 4
// 378.496 us; speedup vs baseline: 1.6746x; 1.1152x over previous
//
#include <hip/hip_runtime.h>
#include <math.h>

// Problem constants
#define BATCH 8
#define CH    256
#define HDIM  56
#define WDIM  56
#define HW    (HDIM*WDIM)          // 3136
#define MTOT  (BATCH*HW)           // 25088
#define GRP   8
#define GC    32
#define NP    9                    // K*K
#define NOFF  (GRP*NP*2)           // 144
#define NMSK  (GRP*NP)             // 72
#define POSB  4                    // positions per sample block

// ---------------------------------------------------------------------------
// GEMM 1: v[m][n] = sum_k x[b][k][hw] * w_in[k][n] + b_in[n]
// 4x4 micro-tile, both fragments contiguous (b128 LDS reads), float4 stores.
// ---------------------------------------------------------------------------
__global__ __launch_bounds__(256)
void gemm_in_kernel(const float* __restrict__ x,
                    const float* __restrict__ w_in,
                    const float* __restrict__ b_in,
                    float* __restrict__ v)
{
    __shared__ alignas(16) float As[16][64];
    __shared__ alignas(16) float Bs[16][64];
    const int m0 = blockIdx.x * 64;
    const int n0 = blockIdx.y * 64;
    const int b  = m0 / HW;          // 3136 % 64 == 0: tile never crosses batch
    const int hw0 = m0 % HW;
    const int t = threadIdx.x;
    const int lk  = t >> 4;          // 0..15
    const int l4  = (t & 15) * 4;    // 0..60
    const int tn4 = (t & 15) * 4, tm4 = (t >> 4) * 4;
    float acc[4][4] = {};

    const float4 bias4 = *(const float4*)&b_in[n0 + tn4];

    for (int k0 = 0; k0 < CH; k0 += 16) {
        const float4 a4 = *(const float4*)(x + ((size_t)b*CH + k0 + lk)*HW + hw0 + l4);
        const float4 b4 = *(const float4*)(w_in + (size_t)(k0 + lk)*CH + n0 + l4);
        *(float4*)&As[lk][l4] = a4;
        *(float4*)&Bs[lk][l4] = b4;
        __syncthreads();
        #pragma unroll
        for (int kk = 0; kk < 16; ++kk) {
            const float4 a = *(const float4*)&As[kk][tm4];
            const float4 bv = *(const float4*)&Bs[kk][tn4];
            #pragma unroll
            for (int i = 0; i < 4; ++i) {
                const float av = ((const float*)&a)[i];
                #pragma unroll
                for (int j = 0; j < 4; ++j) acc[i][j] += av * ((const float*)&bv)[j];
            }
        }
        __syncthreads();
    }
    #pragma unroll
    for (int i = 0; i < 4; ++i) {
        const int m = m0 + tm4 + i;
        float4 o;
        o.x = acc[i][0] + bias4.x; o.y = acc[i][1] + bias4.y;
        o.z = acc[i][2] + bias4.z; o.w = acc[i][3] + bias4.w;
        *(float4*)&v[(size_t)m*CH + n0 + tn4] = o;
    }
}

// ---------------------------------------------------------------------------
// Fused depthwise 3x3 + bias + LayerNorm(C) + exact GELU -> f (NHWC)
// ---------------------------------------------------------------------------
__global__ __launch_bounds__(256)
void dw_ln_gelu_kernel(const float* __restrict__ x,
                       const float* __restrict__ dw_w,
                       const float* __restrict__ dw_b,
                       const float* __restrict__ ln_g,
                       const float* __restrict__ ln_b,
                       float* __restrict__ f)
{
    __shared__ float tile[WDIM][CH + 1];    // 56 x 257 floats (57.5 KB)
    __shared__ float red1[WDIM][4], red2[WDIM][4];
    __shared__ float meanA[WDIM], rstdA[WDIM];

    const int h = blockIdx.x;
    const int b = blockIdx.y;
    const int t = threadIdx.x;
    const int lane = t & 63;
    const int wv   = t >> 6;               // wave id 0..3

    // ---- Phase 1: depthwise conv, 4 channels (one per wave) per iteration
    for (int cg = 0; cg < CH / 4; ++cg) {
        const int c = cg * 4 + wv;
        const float* xp = x + ((size_t)b * CH + c) * HW;
        float rowv[3];
        #pragma unroll
        for (int r = 0; r < 3; ++r) {
            const int hh = h + r - 1;
            rowv[r] = (lane < WDIM && hh >= 0 && hh < HDIM) ? xp[hh * WDIM + lane] : 0.0f;
        }
        const float* wp = dw_w + c * 9;     // wave-uniform -> scalar loads
        float acc = dw_b[c];
        #pragma unroll
        for (int r = 0; r < 3; ++r) {
            float L = __shfl_up(rowv[r], 1);
            float R = __shfl_down(rowv[r], 1);
            if (lane == 0) L = 0.0f;
            acc += L * wp[r * 3 + 0] + rowv[r] * wp[r * 3 + 1] + R * wp[r * 3 + 2];
        }
        if (lane < WDIM)
            tile[lane][c] = acc;
    }
    __syncthreads();

    // ---- Phase 2: LN statistics per position
    if (t < 224) {
        const int p = t >> 2, q = t & 3;
        float s1 = 0.0f, s2 = 0.0f;
        #pragma unroll 8
        for (int i = 0; i < 64; ++i) {
            const float v = tile[p][q * 64 + i];
            s1 += v; s2 += v * v;
        }
        red1[p][q] = s1; red2[p][q] = s2;
    }
    __syncthreads();
    if (t < WDIM) {
        const float s1 = red1[t][0] + red1[t][1] + red1[t][2] + red1[t][3];
        const float s2 = red2[t][0] + red2[t][1] + red2[t][2] + red2[t][3];
        const float m = s1 * (1.0f / 256.0f);
        const float var = s2 * (1.0f / 256.0f) - m * m;
        meanA[t] = m;
        rstdA[t] = rsqrtf(var + 1e-5f);
    }
    __syncthreads();

    // ---- Phase 3: normalize + GELU + coalesced NHWC store
    const float gam = ln_g[t], bet = ln_b[t];
    const size_t n0 = (size_t)(b * HDIM + h) * WDIM;
    for (int p = 0; p < WDIM; ++p) {
        const float xn = (tile[p][t] - meanA[p]) * rstdA[p] * gam + bet;
        const float g = 0.5f * xn * (1.0f + erff(xn * 0.70710678118654752f));
        f[(n0 + p) * CH + t] = g;
    }
}

// ---------------------------------------------------------------------------
// GEMM (A row-major [M,256]) -> Cout [M,N] = A @ Bw + bias. 4x4 micro-tile.
// ---------------------------------------------------------------------------
__global__ __launch_bounds__(256)
void gemm_rowA_kernel(const float* __restrict__ A,
                      const float* __restrict__ Bw,
                      const float* __restrict__ bias,
                      float* __restrict__ Cout,
                      const int N)
{
    __shared__ alignas(16) float As[16][68];   // padded: transposed staging
    __shared__ alignas(16) float Bs[16][64];
    const int m0 = blockIdx.x * 64;
    const int n0 = blockIdx.y * 64;
    const int t = threadIdx.x;
    const int am = t >> 2, ak4 = (t & 3) * 4;      // A tile load
    const int lk = t >> 4, ln4 = (t & 15) * 4;     // B tile load
    const int tn4 = (t & 15) * 4, tm4 = (t >> 4) * 4;
    float acc[4][4] = {};

    float bias4[4];
    #pragma unroll
    for (int j = 0; j < 4; ++j)
        bias4[j] = (n0 + tn4 + j < N) ? bias[n0 + tn4 + j] : 0.0f;

    for (int k0 = 0; k0 < CH; k0 += 16) {
        const float4 a4 = *(const float4*)(A + (size_t)(m0 + am)*CH + k0 + ak4);
        float4 bb;
        #pragma unroll
        for (int j = 0; j < 4; ++j) {
            const int nn = n0 + ln4 + j;
            ((float*)&bb)[j] = (nn < N) ? Bw[(size_t)(k0 + lk)*N + nn] : 0.0f;
        }
        #pragma unroll
        for (int j = 0; j < 4; ++j) As[ak4 + j][am] = ((const float*)&a4)[j];
        *(float4*)&Bs[lk][ln4] = bb;
        __syncthreads();
        #pragma unroll
        for (int kk = 0; kk < 16; ++kk) {
            const float4 a = *(const float4*)&As[kk][tm4];
            const float4 bv = *(const float4*)&Bs[kk][tn4];
            #pragma unroll
            for (int i = 0; i < 4; ++i) {
                const float av = ((const float*)&a)[i];
                #pragma unroll
                for (int j = 0; j < 4; ++j) acc[i][j] += av * ((const float*)&bv)[j];
            }
        }
        __syncthreads();
    }
    if (n0 + tn4 < N) {
        #pragma unroll
        for (int i = 0; i < 4; ++i) {
            const int m = m0 + tm4 + i;
            float4 o;
            o.x = acc[i][0] + bias4[0]; o.y = acc[i][1] + bias4[1];
            o.z = acc[i][2] + bias4[2]; o.w = acc[i][3] + bias4[3];
            *(float4*)&Cout[(size_t)m*N + n0 + tn4] = o;
        }
    }
}

// ---------------------------------------------------------------------------
// Deformable sampling, restructured: block = 4 positions x 64 lanes.
// Group-uniform work (softmax, bilinear weights incl. validity & mask,
// corner offsets) precomputed cooperatively into LDS; inner loop per lane is
// 2 b128 LDS reads + 4 float4 global loads + 16 FMA per tap. Lane owns 4
// consecutive channels (g = lane>>3 uniform across its 4 channels).
// ---------------------------------------------------------------------------
__global__ __launch_bounds__(256)
void sample_kernel(const float* __restrict__ v,
                   const float* __restrict__ offb,
                   const float* __restrict__ mskb,
                   float* __restrict__ s)
{
    __shared__ alignas(16) float loff[POSB][NOFF];
    __shared__ alignas(16) float lmsk[POSB][NMSK];
    __shared__ alignas(16) float wtab[POSB][GRP*NP][4];
    __shared__ alignas(16) int   itab[POSB][GRP*NP][4];

    const int n0 = blockIdx.x * POSB;
    const int t = threadIdx.x;

    // Phase 1: bulk float4 loads of offsets + masks for 4 positions
    if (t < POSB * (NOFF/4)) {                 // 144 threads
        const int q = t / (NOFF/4), r = t % (NOFF/4);
        *(float4*)&loff[q][r*4] = *(const float4*)&offb[(size_t)(n0+q)*NOFF + r*4];
    } else if (t < POSB * (NOFF/4) + POSB * (NMSK/4)) {   // next 72 threads
        const int u = t - POSB * (NOFF/4);
        const int q = u / (NMSK/4), r = u % (NMSK/4);
        *(float4*)&lmsk[q][r*4] = *(const float4*)&mskb[(size_t)(n0+q)*NMSK + r*4];
    }
    __syncthreads();

    // Phase 2: softmax per (pos, group): 32 active threads
    if (t < POSB * GRP) {
        const int q = t >> 3, g = t & 7;
        float* mm = &lmsk[q][g * NP];
        float mx = -1e30f;
        #pragma unroll
        for (int p = 0; p < NP; ++p) mx = fmaxf(mx, mm[p]);
        float sum = 0.0f;
        #pragma unroll
        for (int p = 0; p < NP; ++p) { const float e = __expf(mm[p] - mx); mm[p] = e; sum += e; }
        const float inv = 1.0f / sum;
        #pragma unroll
        for (int p = 0; p < NP; ++p) mm[p] *= inv;
    }
    __syncthreads();

    // Phase 3: per (pos, g, p) weights (mask & validity folded) + offsets
    for (int u = t; u < POSB * GRP * NP; u += 256) {      // 288 slots
        const int q = u / (GRP*NP), j = u % (GRP*NP);
        const int g = j / NP, p = j % NP;
        const int n = n0 + q;
        const int hw = n % HW;
        const int h = hw / WDIM, w = hw % WDIM;
        const float ox = loff[q][g*18 + p*2 + 0];
        const float oy = loff[q][g*18 + p*2 + 1];
        const float m  = lmsk[q][g*NP + p];
        const float px = (float)(w + p/3) + ox;       // padded coords
        const float py = (float)(h + p%3) + oy;
        const float fx = floorf(px), fy = floorf(py);
        const float wx = px - fx, wy = py - fy;
        const int x0 = (int)fx, y0 = (int)fy;
        const int x1 = x0 + 1, y1 = y0 + 1;
        const float vx0 = (x0 >= 1 && x0 < 57) ? 1.0f : 0.0f;
        const float vx1 = (x1 >= 1 && x1 < 57) ? 1.0f : 0.0f;
        const float vy0 = (y0 >= 1 && y0 < 57) ? 1.0f : 0.0f;
        const float vy1 = (y1 >= 1 && y1 < 57) ? 1.0f : 0.0f;
        const int x0c = min(max(x0, 1), 56), x1c = min(max(x1, 1), 56);
        const int y0c = min(max(y0, 1), 56), y1c = min(max(y1, 1), 56);
        wtab[q][j][0] = m * (1.0f-wx) * (1.0f-wy) * vx0 * vy0;
        wtab[q][j][1] = m * wx        * (1.0f-wy) * vx1 * vy0;
        wtab[q][j][2] = m * (1.0f-wx) * wy        * vx0 * vy1;
        wtab[q][j][3] = m * wx        * wy        * vx1 * vy1;
        itab[q][j][0] = ((y0c-1)*WDIM + (x0c-1)) * CH;
        itab[q][j][1] = ((y0c-1)*WDIM + (x1c-1)) * CH;
        itab[q][j][2] = ((y1c-1)*WDIM + (x0c-1)) * CH;
        itab[q][j][3] = ((y1c-1)*WDIM + (x1c-1)) * CH;
    }
    __syncthreads();

    // Phase 4: accumulation. Wave q handles position n0+q; lane owns 4 ch.
    const int q = t >> 6, lane = t & 63;
    const int n = n0 + q;
    const int b = n / HW;
    const int g = lane >> 3;
    const float* vb = v + (size_t)b*HW*CH + lane*4;
    float4 acc = {0.0f, 0.0f, 0.0f, 0.0f};
    #pragma unroll
    for (int p = 0; p < NP; ++p) {
        const int j = g*NP + p;
        const float4 wv = *(const float4*)&wtab[q][j][0];
        const int4  iv = *(const int4*)&itab[q][j][0];
        const float4 c0 = *(const float4*)(vb + iv.x);
        const float4 c1 = *(const float4*)(vb + iv.y);
        const float4 c2 = *(const float4*)(vb + iv.z);
        const float4 c3 = *(const float4*)(vb + iv.w);
        acc.x += wv.x*c0.x + wv.y*c1.x + wv.z*c2.x + wv.w*c3.x;
        acc.y += wv.x*c0.y + wv.y*c1.y + wv.z*c2.y + wv.w*c3.y;
        acc.z += wv.x*c0.z + wv.y*c1.z + wv.z*c2.z + wv.w*c3.z;
        acc.w += wv.x*c0.w + wv.y*c1.w + wv.z*c2.w + wv.w*c3.w;
    }
    *(float4*)&s[(size_t)n*CH + lane*4] = acc;
}

// ---------------------------------------------------------------------------
// GEMM out: y = SiLU(BN(s @ w_out + b_out)), stored NCHW. 4x4 micro-tile;
// epilogue stores float4 along hw (contiguous in NCHW).
// ---------------------------------------------------------------------------
__global__ __launch_bounds__(256)
void gemm_out_kernel(const float* __restrict__ A,     // s [MTOT,256]
                     const float* __restrict__ Bw,    // w_out [256,256]
                     const float* __restrict__ bias,  // b_out
                     const float* __restrict__ bn_g,
                     const float* __restrict__ bn_b,
                     const float* __restrict__ bn_mean,
                     const float* __restrict__ bn_var,
                     float* __restrict__ y)           // [B,256,3136]
{
    __shared__ alignas(16) float As[16][68];   // padded transposed staging
    __shared__ alignas(16) float Bs[16][64];
    const int m0 = blockIdx.x * 64;
    const int n0 = blockIdx.y * 64;
    const int t = threadIdx.x;
    const int am = t >> 2, ak4 = (t & 3) * 4;
    const int lk = t >> 4, ln4 = (t & 15) * 4;
    const int tm4 = (t >> 4) * 4, tn4 = (t & 15) * 4;  // rows(hw) / cols(ch)
    float acc[4][4] = {};                               // [row i][col j]

    for (int k0 = 0; k0 < CH; k0 += 16) {
        const float4 a4 = *(const float4*)(A + (size_t)(m0 + am)*CH + k0 + ak4);
        const float4 b4 = *(const float4*)(Bw + (size_t)(k0 + lk)*CH + n0 + ln4);
        #pragma unroll
        for (int j = 0; j < 4; ++j) As[ak4 + j][am] = ((const float*)&a4)[j];
        *(float4*)&Bs[lk][ln4] = b4;
        __syncthreads();
        #pragma unroll
        for (int kk = 0; kk < 16; ++kk) {
            const float4 a = *(const float4*)&As[kk][tm4];
            const float4 bv = *(const float4*)&Bs[kk][tn4];
            #pragma unroll
            for (int i = 0; i < 4; ++i) {
                const float av = ((const float*)&a)[i];
                #pragma unroll
                for (int j = 0; j < 4; ++j) acc[i][j] += av * ((const float*)&bv)[j];
            }
        }
        __syncthreads();
    }
    const int b = m0 / HW;
    const int hw0 = m0 % HW;
    #pragma unroll
    for (int j = 0; j < 4; ++j) {
        const int nn = n0 + tn4 + j;
        const float sc = bn_g[nn] * rsqrtf(bn_var[nn] + 1e-5f);
        const float sh = bn_b[nn] - bn_mean[nn] * sc;
        const float bs = bias[nn];
        float4 o;
        #pragma unroll
        for (int i = 0; i < 4; ++i) {
            float val = acc[i][j] + bs;
            val = val * sc + sh;
            ((float*)&o)[i] = val / (1.0f + expf(-val));   // SiLU
        }
        *(float4*)&y[((size_t)b*CH + nn)*HW + hw0 + tm4] = o;
    }
}

extern "C" void kernel_launch(void* const* d_in, const int* in_sizes, int n_in,
                              void* d_out, int out_size, void* d_ws, size_t ws_size,
                              hipStream_t stream) {
    const float* x      = (const float*)d_in[0];
    const float* w_in   = (const float*)d_in[1];
    const float* b_in   = (const float*)d_in[2];
    const float* dw_w   = (const float*)d_in[3];
    const float* dw_b   = (const float*)d_in[4];
    const float* ln_g   = (const float*)d_in[5];
    const float* ln_b   = (const float*)d_in[6];
    const float* w_off  = (const float*)d_in[7];
    const float* b_off  = (const float*)d_in[8];
    const float* w_mask = (const float*)d_in[9];
    const float* b_mask = (const float*)d_in[10];
    const float* w_out  = (const float*)d_in[11];
    const float* b_out  = (const float*)d_in[12];
    const float* bn_g   = (const float*)d_in[13];
    const float* bn_b   = (const float*)d_in[14];
    const float* bn_mean= (const float*)d_in[15];
    const float* bn_var = (const float*)d_in[16];
    float* out = (float*)d_out;

    float* ws   = (float*)d_ws;
    float* v    = ws;                                   // MTOT*CH
    float* f    = v + (size_t)MTOT*CH;                  // MTOT*CH
    float* offb = f + (size_t)MTOT*CH;                  // MTOT*NOFF
    float* mskb = offb + (size_t)MTOT*NOFF;             // MTOT*NMSK
    float* s    = f;                                    // reuse f buffer

    const dim3 blk(256);
    gemm_in_kernel<<<dim3(MTOT/64, CH/64), blk, 0, stream>>>(x, w_in, b_in, v);
    dw_ln_gelu_kernel<<<dim3(HDIM, BATCH), blk, 0, stream>>>(x, dw_w, dw_b, ln_g, ln_b, f);
    gemm_rowA_kernel<<<dim3(MTOT/64, (NOFF + 63)/64), blk, 0, stream>>>(f, w_off, b_off, offb, NOFF);
    gemm_rowA_kernel<<<dim3(MTOT/64, (NMSK + 63)/64), blk, 0, stream>>>(f, w_mask, b_mask, mskb, NMSK);
    sample_kernel<<<dim3(MTOT/POSB), blk, 0, stream>>>(v, offb, mskb, s);
    gemm_out_kernel<<<dim3(MTOT/64, CH/64), blk, 0, stream>>>(s, w_out, b_out, bn_g, bn_b, bn_mean, bn_var, out);
}